// Round 1
// baseline (1946.462 us; speedup 1.0000x reference)
//
#include <hip/hip_runtime.h>

namespace {

constexpr int H_   = 128;
constexpr int E_   = 1000000;
constexpr int EB   = 64;     // edges per workgroup
constexpr int NT   = 256;    // threads per workgroup
constexpr int NTIL = E_ / EB; // 15625 (exact)

struct P1 {
    float At[32][EB];     // A^T k-chunk: [k_local][edge]   8 KB
    float W1c[32][H_];    // W1 k-chunk: [k_local][col]    16 KB
};
struct P2 {
    float h[EB][H_ + 4];  // post-LN/ReLU activations      33.8 KB
    float W2c[H_][64];    // full W2                       32 KB
};
union Smem { P1 p1; P2 p2; };

__global__ __launch_bounds__(NT, 2)
void edge_mlp(const float* __restrict__ node_embed,
              const int*   __restrict__ eidx,     // [2][E] int32
              const float* __restrict__ attr,     // [E][2]
              const float* __restrict__ W1,       // [258][128]
              const float* __restrict__ b1,       // [128]
              const float* __restrict__ gamma,    // [128]
              const float* __restrict__ beta,     // [128]
              const float* __restrict__ W2,       // [128][64]
              const float* __restrict__ b2,       // [64]
              const float* __restrict__ W3,       // [64]
              const float* __restrict__ b3,       // [1]
              float* __restrict__ out)            // [E]
{
    __shared__ Smem sm;
    __shared__ int   idx_i[EB];
    __shared__ int   idx_j[EB];
    __shared__ float attr_s[EB][2];
    __shared__ float W1t[2][H_];   // W1 rows 256,257 (edge-attr rows)

    const int tid   = threadIdx.x;
    const int ebase = blockIdx.x * EB;

    // ---- stage indices / attrs / W1 tail rows ----
    if (tid < EB) {
        idx_i[tid] = eidx[ebase + tid];
    } else if (tid < 2 * EB) {
        idx_j[tid - EB] = eidx[E_ + ebase + (tid - EB)];
    } else if (tid < 3 * EB) {
        int e = tid - 2 * EB;
        float2 a2 = *reinterpret_cast<const float2*>(attr + (size_t)(ebase + e) * 2);
        attr_s[e][0] = a2.x;
        attr_s[e][1] = a2.y;
    } else {
        int r = tid - 3 * EB;  // 0..63, 4 floats each -> 256 floats
        float4 v = *reinterpret_cast<const float4*>(W1 + 256 * H_ + r * 4);
        *reinterpret_cast<float4*>(&W1t[0][0] + r * 4) = v;
    }
    __syncthreads();

    // ---- GEMM1 mapping: thread = (cgrp, egrp) -> 4 cols x 8 edges ----
    const int cgrp = tid & 31;    // col group: cols 4*cgrp..+3
    const int egrp = tid >> 5;    // edge group: edges 8*egrp..+7
    const int c0   = cgrp * 4;
    const int e0   = egrp * 8;

    float acc[8][4];
#pragma unroll
    for (int i = 0; i < 8; ++i)
#pragma unroll
        for (int j = 0; j < 4; ++j) acc[i][j] = 0.f;

    const int ge = tid >> 2;  // gather: edge handled by this thread
    const int gq = tid & 3;   // which 8-element span of the 32-k chunk

    for (int chunk = 0; chunk < 8; ++chunk) {
        const int  kbase = chunk * 32;
        const int* idx   = (chunk < 4) ? idx_i : idx_j;
        const int  ebias = (chunk < 4) ? kbase : (kbase - 128);

        // gather A^T chunk [32][64]
        {
            int row = idx[ge];
            const float* src = node_embed + (size_t)row * H_ + ebias + gq * 8;
            float4 v0 = *reinterpret_cast<const float4*>(src);
            float4 v1 = *reinterpret_cast<const float4*>(src + 4);
            int kl = gq * 8;
            sm.p1.At[kl + 0][ge] = v0.x;
            sm.p1.At[kl + 1][ge] = v0.y;
            sm.p1.At[kl + 2][ge] = v0.z;
            sm.p1.At[kl + 3][ge] = v0.w;
            sm.p1.At[kl + 4][ge] = v1.x;
            sm.p1.At[kl + 5][ge] = v1.y;
            sm.p1.At[kl + 6][ge] = v1.z;
            sm.p1.At[kl + 7][ge] = v1.w;
        }
        // stage W1 chunk [32][128] = 1024 float4
        {
            const float4* srcW = reinterpret_cast<const float4*>(W1 + kbase * H_);
            float4* dstW = reinterpret_cast<float4*>(&sm.p1.W1c[0][0]);
#pragma unroll
            for (int r = 0; r < 4; ++r) dstW[r * NT + tid] = srcW[r * NT + tid];
        }
        __syncthreads();

#pragma unroll 8
        for (int k = 0; k < 32; ++k) {
            float4 b  = *reinterpret_cast<const float4*>(&sm.p1.W1c[k][c0]);
            float4 a0 = *reinterpret_cast<const float4*>(&sm.p1.At[k][e0]);
            float4 a1 = *reinterpret_cast<const float4*>(&sm.p1.At[k][e0 + 4]);
            float av[8] = {a0.x, a0.y, a0.z, a0.w, a1.x, a1.y, a1.z, a1.w};
#pragma unroll
            for (int i = 0; i < 8; ++i) {
                acc[i][0] = fmaf(av[i], b.x, acc[i][0]);
                acc[i][1] = fmaf(av[i], b.y, acc[i][1]);
                acc[i][2] = fmaf(av[i], b.z, acc[i][2]);
                acc[i][3] = fmaf(av[i], b.w, acc[i][3]);
            }
        }
        __syncthreads();  // before next chunk overwrites At/W1c
    }

    // ---- edge-attr tail (k = 256,257) ----
    {
        float4 w0 = *reinterpret_cast<const float4*>(&W1t[0][c0]);
        float4 w1 = *reinterpret_cast<const float4*>(&W1t[1][c0]);
#pragma unroll
        for (int i = 0; i < 8; ++i) {
            float a0 = attr_s[e0 + i][0];
            float a1 = attr_s[e0 + i][1];
            acc[i][0] += a0 * w0.x + a1 * w1.x;
            acc[i][1] += a0 * w0.y + a1 * w1.y;
            acc[i][2] += a0 * w0.z + a1 * w1.z;
            acc[i][3] += a0 * w0.w + a1 * w1.w;
        }
    }

    // ---- +b1, LayerNorm (over 128 cols, 32-lane butterfly), ReLU ----
    float4 b1v = *reinterpret_cast<const float4*>(b1 + c0);
    float4 gv  = *reinterpret_cast<const float4*>(gamma + c0);
    float4 bv  = *reinterpret_cast<const float4*>(beta + c0);

    float hreg[8][4];
#pragma unroll
    for (int i = 0; i < 8; ++i) {
        float x0 = acc[i][0] + b1v.x;
        float x1 = acc[i][1] + b1v.y;
        float x2 = acc[i][2] + b1v.z;
        float x3 = acc[i][3] + b1v.w;
        float s1 = x0 + x1 + x2 + x3;
        float s2 = x0 * x0 + x1 * x1 + x2 * x2 + x3 * x3;
#pragma unroll
        for (int off = 16; off >= 1; off >>= 1) {
            s1 += __shfl_xor(s1, off);
            s2 += __shfl_xor(s2, off);
        }
        float mean = s1 * (1.f / 128.f);
        float var  = s2 * (1.f / 128.f) - mean * mean;
        float rstd = rsqrtf(var + 1e-5f);
        hreg[i][0] = fmaxf((x0 - mean) * rstd * gv.x + bv.x, 0.f);
        hreg[i][1] = fmaxf((x1 - mean) * rstd * gv.y + bv.y, 0.f);
        hreg[i][2] = fmaxf((x2 - mean) * rstd * gv.z + bv.z, 0.f);
        hreg[i][3] = fmaxf((x3 - mean) * rstd * gv.w + bv.w, 0.f);
    }

    // ---- write h to LDS (phase-1 LDS is dead: last loop iter ended in syncthreads) ----
#pragma unroll
    for (int i = 0; i < 8; ++i) {
        *reinterpret_cast<float4*>(&sm.p2.h[e0 + i][c0]) =
            make_float4(hreg[i][0], hreg[i][1], hreg[i][2], hreg[i][3]);
    }
    // stage full W2 [128][64] = 2048 float4 (region doesn't overlap phase-1 LDS footprint)
    {
        const float4* srcW = reinterpret_cast<const float4*>(W2);
        float4* dstW = reinterpret_cast<float4*>(&sm.p2.W2c[0][0]);
#pragma unroll
        for (int r = 0; r < 8; ++r) dstW[r * NT + tid] = srcW[r * NT + tid];
    }
    __syncthreads();

    // ---- GEMM2: thread = (cgrp2, egrp2) -> 4 cols x 4 edges ----
    const int cgrp2 = tid & 15;
    const int egrp2 = tid >> 4;
    const int c2 = cgrp2 * 4;
    const int e2 = egrp2 * 4;

    float acc2[4][4];
#pragma unroll
    for (int i = 0; i < 4; ++i)
#pragma unroll
        for (int j = 0; j < 4; ++j) acc2[i][j] = 0.f;

#pragma unroll 4
    for (int k4 = 0; k4 < H_; k4 += 4) {
        float4 bb0 = *reinterpret_cast<const float4*>(&sm.p2.W2c[k4 + 0][c2]);
        float4 bb1 = *reinterpret_cast<const float4*>(&sm.p2.W2c[k4 + 1][c2]);
        float4 bb2 = *reinterpret_cast<const float4*>(&sm.p2.W2c[k4 + 2][c2]);
        float4 bb3 = *reinterpret_cast<const float4*>(&sm.p2.W2c[k4 + 3][c2]);
#pragma unroll
        for (int i = 0; i < 4; ++i) {
            float4 aa = *reinterpret_cast<const float4*>(&sm.p2.h[e2 + i][k4]);
            acc2[i][0] = fmaf(aa.x, bb0.x, acc2[i][0]);
            acc2[i][1] = fmaf(aa.x, bb0.y, acc2[i][1]);
            acc2[i][2] = fmaf(aa.x, bb0.z, acc2[i][2]);
            acc2[i][3] = fmaf(aa.x, bb0.w, acc2[i][3]);
            acc2[i][0] = fmaf(aa.y, bb1.x, acc2[i][0]);
            acc2[i][1] = fmaf(aa.y, bb1.y, acc2[i][1]);
            acc2[i][2] = fmaf(aa.y, bb1.z, acc2[i][2]);
            acc2[i][3] = fmaf(aa.y, bb1.w, acc2[i][3]);
            acc2[i][0] = fmaf(aa.z, bb2.x, acc2[i][0]);
            acc2[i][1] = fmaf(aa.z, bb2.y, acc2[i][1]);
            acc2[i][2] = fmaf(aa.z, bb2.z, acc2[i][2]);
            acc2[i][3] = fmaf(aa.z, bb2.w, acc2[i][3]);
            acc2[i][0] = fmaf(aa.w, bb3.x, acc2[i][0]);
            acc2[i][1] = fmaf(aa.w, bb3.y, acc2[i][1]);
            acc2[i][2] = fmaf(aa.w, bb3.z, acc2[i][2]);
            acc2[i][3] = fmaf(aa.w, bb3.w, acc2[i][3]);
        }
    }

    // ---- +b2, ReLU, layer 3 dot with W3, 16-lane reduce, +b3, store ----
    float4 b2v = *reinterpret_cast<const float4*>(b2 + c2);
    float4 w3v = *reinterpret_cast<const float4*>(W3 + c2);
    float  b3s = b3[0];

    float part[4];
#pragma unroll
    for (int i = 0; i < 4; ++i) {
        float z0 = fmaxf(acc2[i][0] + b2v.x, 0.f);
        float z1 = fmaxf(acc2[i][1] + b2v.y, 0.f);
        float z2 = fmaxf(acc2[i][2] + b2v.z, 0.f);
        float z3 = fmaxf(acc2[i][3] + b2v.w, 0.f);
        part[i] = z0 * w3v.x + z1 * w3v.y + z2 * w3v.z + z3 * w3v.w;
    }
#pragma unroll
    for (int off = 8; off >= 1; off >>= 1) {
#pragma unroll
        for (int i = 0; i < 4; ++i) part[i] += __shfl_xor(part[i], off);
    }
    if (cgrp2 == 0) {
        float4 o = make_float4(part[0] + b3s, part[1] + b3s, part[2] + b3s, part[3] + b3s);
        *reinterpret_cast<float4*>(out + ebase + e2) = o;
    }
}

} // namespace

extern "C" void kernel_launch(void* const* d_in, const int* in_sizes, int n_in,
                              void* d_out, int out_size, void* d_ws, size_t ws_size,
                              hipStream_t stream) {
    const float* node_embed = (const float*)d_in[0];
    const int*   eidx       = (const int*)  d_in[1];
    const float* attr       = (const float*)d_in[2];
    const float* W1         = (const float*)d_in[3];
    const float* b1         = (const float*)d_in[4];
    const float* gamma      = (const float*)d_in[5];
    const float* beta       = (const float*)d_in[6];
    const float* W2         = (const float*)d_in[7];
    const float* b2         = (const float*)d_in[8];
    const float* W3         = (const float*)d_in[9];
    const float* b3         = (const float*)d_in[10];
    float* out = (float*)d_out;

    edge_mlp<<<NTIL, NT, 0, stream>>>(node_embed, eidx, attr, W1, b1, gamma, beta,
                                      W2, b2, W3, b3, out);
}

// Round 2
// 274.416 us; speedup vs baseline: 7.0931x; 7.0931x over previous
//
#include <hip/hip_runtime.h>

typedef __attribute__((ext_vector_type(8))) short short8;
typedef __attribute__((ext_vector_type(4))) float f32x4;
typedef unsigned short ushort_t;

namespace {

constexpr int H     = 128;
constexpr int E     = 1000000;
constexpr int NNODE = 100000;
constexpr int EB    = 256;                   // edges per block
constexpr int NBLK  = (E + EB - 1) / EB;     // 3907 (last block: 64 valid edges)

// d_ws layout
constexpr size_t NB_OFF  = 0;                                  // bf16 nodes: 100000*128*2 = 25,600,000 B
constexpr size_t W1F_OFF = (size_t)NNODE * H * 2;              // W1 frags: 64 KB
constexpr size_t W2F_OFF = W1F_OFF + 64 * 1024;                // W2 frags: 16 KB
constexpr size_t WS_NEED = W2F_OFF + 16 * 1024;

__device__ __forceinline__ ushort_t f2bf(float x) {
    unsigned u = __float_as_uint(x);
    return (ushort_t)((u + 0x7FFFu + ((u >> 16) & 1u)) >> 16);
}
__device__ __forceinline__ int imin(int a, int b) { return a < b ? a : b; }

// ---- prep 1: node_embed fp32 -> bf16 table ----
__global__ void cvt_nodes(const float* __restrict__ src, ushort_t* __restrict__ dst, int n4) {
    int i = blockIdx.x * blockDim.x + threadIdx.x;
    int stride = gridDim.x * blockDim.x;
    for (; i < n4; i += stride) {
        float4 v = reinterpret_cast<const float4*>(src)[i];
        ushort4 o;
        o.x = f2bf(v.x); o.y = f2bf(v.y); o.z = f2bf(v.z); o.w = f2bf(v.w);
        reinterpret_cast<ushort4*>(dst)[i] = o;
    }
}

// ---- prep 2: W1/W2 -> bf16 MFMA B-fragment layout ----
// Unit u (K-step s, N-tile n): lane l holds B[k = s*32 + (l>>4)*8 + j][col = n*16 + (l&15)], j=0..7.
__global__ void cvt_wfrag(const float* __restrict__ W1, const float* __restrict__ W2,
                          ushort_t* __restrict__ w1f, ushort_t* __restrict__ w2f) {
    int u = blockIdx.x, l = threadIdx.x;
    int lo = l & 15, hi = l >> 4;
    if (u < 64) {                       // W1: 8 K-steps x 8 N-tiles
        int s = u >> 3, n = u & 7;
#pragma unroll
        for (int j = 0; j < 8; ++j)
            w1f[(u * 64 + l) * 8 + j] = f2bf(W1[(s * 32 + hi * 8 + j) * 128 + n * 16 + lo]);
    } else {                            // W2: 4 K-steps x 4 N-tiles
        int u2 = u - 64;
        int s = u2 >> 2, n = u2 & 3;
#pragma unroll
        for (int j = 0; j < 8; ++j)
            w2f[(u2 * 64 + l) * 8 + j] = f2bf(W2[(s * 32 + hi * 8 + j) * 64 + n * 16 + lo]);
    }
}

// ---- main kernel ----
struct SmemT {
    ushort_t w1f[32768];        // 64 KB  W1 fragments
    ushort_t w2f[8192];         // 16 KB  W2 fragments
    ushort_t hbuf[8][32 * 136]; // 68 KB  per-wave h (stride 136 elems = 272 B)
    int      idxs[2][EB];       // 2 KB
    float    attrs[EB][2];      // 2 KB
    float    b1s[H], w1t0[H], w1t1[H], gs[H], bs[H];
    float    b2s[64], w3s[64];
};                              // total 158,720 B

__global__ __launch_bounds__(512, 2)
void edge_mlp_mfma(const ushort_t* __restrict__ nb,
                   const ushort_t* __restrict__ w1fg,
                   const ushort_t* __restrict__ w2fg,
                   const int*      __restrict__ eidx,   // [2][E] int32
                   const float*    __restrict__ attr,   // [E][2]
                   const float*    __restrict__ W1,     // rows 256/257 used fp32
                   const float*    __restrict__ b1,
                   const float*    __restrict__ gamma_,
                   const float*    __restrict__ beta_,
                   const float*    __restrict__ b2,
                   const float*    __restrict__ W3,
                   const float*    __restrict__ b3,
                   float*          __restrict__ out) {
    __shared__ SmemT sm;
    const int tid = threadIdx.x;
    const int eb  = blockIdx.x * EB;

    // ---- stage: W1/W2 fragments, indices, attrs, small params ----
    {
        const uint4* s1 = reinterpret_cast<const uint4*>(w1fg);
        uint4*       d1 = reinterpret_cast<uint4*>(sm.w1f);
#pragma unroll
        for (int i = 0; i < 8; ++i) d1[i * 512 + tid] = s1[i * 512 + tid];
        const uint4* s2 = reinterpret_cast<const uint4*>(w2fg);
        uint4*       d2 = reinterpret_cast<uint4*>(sm.w2f);
#pragma unroll
        for (int i = 0; i < 2; ++i) d2[i * 512 + tid] = s2[i * 512 + tid];
    }
    {
        int t = tid & 255;
        int e = imin(eb + t, E - 1);
        if (tid < 256) sm.idxs[0][t] = eidx[e];
        else           sm.idxs[1][t] = eidx[E + e];
        int ea = imin(eb + (tid >> 1), E - 1);
        reinterpret_cast<float*>(sm.attrs)[tid] = attr[(size_t)ea * 2 + (tid & 1)];
    }
    if (tid < 128) {
        sm.b1s[tid]  = b1[tid];
        sm.w1t0[tid] = W1[256 * H + tid];
        sm.w1t1[tid] = W1[257 * H + tid];
        sm.gs[tid]   = gamma_[tid];
        sm.bs[tid]   = beta_[tid];
        if (tid < 64) { sm.b2s[tid] = b2[tid]; sm.w3s[tid] = W3[tid]; }
    }
    __syncthreads();   // the only block-wide barrier

    const int wid  = tid >> 6;
    const int lane = tid & 63;
    const int lo   = lane & 15, hi = lane >> 4;
    const int ebl  = wid * 32;           // wave's local edge base (0..224)

    // ---- A-fragment gather: 16 direct global dwordx4 loads, all in flight ----
    short8 afrag[2][8];
#pragma unroll
    for (int mt = 0; mt < 2; ++mt) {
        int el = ebl + mt * 16 + lo;
        int ni = sm.idxs[0][el];
        int nj = sm.idxs[1][el];
#pragma unroll
        for (int s = 0; s < 4; ++s)
            afrag[mt][s] = *reinterpret_cast<const short8*>(nb + (size_t)ni * H + s * 32 + hi * 8);
#pragma unroll
        for (int s = 0; s < 4; ++s)
            afrag[mt][4 + s] = *reinterpret_cast<const short8*>(nb + (size_t)nj * H + s * 32 + hi * 8);
    }

    // ---- GEMM1: [32 edges] x [K=256] x [128 cols] ----
    f32x4 acc1[2][8];
    const f32x4 zero4 = {0.f, 0.f, 0.f, 0.f};
#pragma unroll
    for (int mt = 0; mt < 2; ++mt)
#pragma unroll
        for (int n = 0; n < 8; ++n) acc1[mt][n] = zero4;

#pragma unroll
    for (int s = 0; s < 8; ++s) {
        short8 bf[8];
#pragma unroll
        for (int n = 0; n < 8; ++n)
            bf[n] = *reinterpret_cast<const short8*>(sm.w1f + ((s * 8 + n) * 64 + lane) * 8);
#pragma unroll
        for (int n = 0; n < 8; ++n) {
            acc1[0][n] = __builtin_amdgcn_mfma_f32_16x16x32_bf16(afrag[0][s], bf[n], acc1[0][n], 0, 0, 0);
            acc1[1][n] = __builtin_amdgcn_mfma_f32_16x16x32_bf16(afrag[1][s], bf[n], acc1[1][n], 0, 0, 0);
        }
    }

    // ---- + b1 + attr-tail (K rows 256,257 in fp32) ----
    float a0v[2][4], a1v[2][4];
#pragma unroll
    for (int mt = 0; mt < 2; ++mt)
#pragma unroll
        for (int r = 0; r < 4; ++r) {
            int el = ebl + mt * 16 + hi * 4 + r;
            a0v[mt][r] = sm.attrs[el][0];
            a1v[mt][r] = sm.attrs[el][1];
        }
#pragma unroll
    for (int n = 0; n < 8; ++n) {
        int col = n * 16 + lo;
        float bb = sm.b1s[col], t0 = sm.w1t0[col], t1 = sm.w1t1[col];
#pragma unroll
        for (int mt = 0; mt < 2; ++mt)
#pragma unroll
            for (int r = 0; r < 4; ++r)
                acc1[mt][n][r] += bb + a0v[mt][r] * t0 + a1v[mt][r] * t1;
    }

    // ---- LayerNorm (wave-local: 16-lane xor-reduce) + ReLU -> h (bf16, per-wave LDS) ----
    float gv[8], bv[8];
#pragma unroll
    for (int n = 0; n < 8; ++n) { gv[n] = sm.gs[n * 16 + lo]; bv[n] = sm.bs[n * 16 + lo]; }

    ushort_t* hw = sm.hbuf[wid];
#pragma unroll
    for (int mt = 0; mt < 2; ++mt) {
#pragma unroll
        for (int r = 0; r < 4; ++r) {
            float s1 = 0.f, s2 = 0.f;
#pragma unroll
            for (int n = 0; n < 8; ++n) { float x = acc1[mt][n][r]; s1 += x; s2 += x * x; }
#pragma unroll
            for (int off = 8; off >= 1; off >>= 1) {
                s1 += __shfl_xor(s1, off);
                s2 += __shfl_xor(s2, off);
            }
            float mean = s1 * (1.f / 128.f);
            float var  = s2 * (1.f / 128.f) - mean * mean;
            float rstd = rsqrtf(var + 1e-5f);
            int row = mt * 16 + hi * 4 + r;
#pragma unroll
            for (int n = 0; n < 8; ++n) {
                float hx = (acc1[mt][n][r] - mean) * rstd * gv[n] + bv[n];
                hx = fmaxf(hx, 0.f);
                hw[row * 136 + n * 16 + lo] = f2bf(hx);
            }
        }
    }
    // wave-local LDS round-trip: in-wave lgkmcnt ordering suffices, no barrier

    // ---- GEMM2: [32 edges] x [K=128] x [64 cols] ----
    f32x4 acc2[2][4];
#pragma unroll
    for (int mt = 0; mt < 2; ++mt)
#pragma unroll
        for (int n = 0; n < 4; ++n) acc2[mt][n] = zero4;

#pragma unroll
    for (int s = 0; s < 4; ++s) {
        short8 bf2[4];
#pragma unroll
        for (int n = 0; n < 4; ++n)
            bf2[n] = *reinterpret_cast<const short8*>(sm.w2f + ((s * 4 + n) * 64 + lane) * 8);
        short8 af2[2];
#pragma unroll
        for (int mt = 0; mt < 2; ++mt)
            af2[mt] = *reinterpret_cast<const short8*>(hw + (mt * 16 + lo) * 136 + s * 32 + hi * 8);
#pragma unroll
        for (int n = 0; n < 4; ++n) {
            acc2[0][n] = __builtin_amdgcn_mfma_f32_16x16x32_bf16(af2[0], bf2[n], acc2[0][n], 0, 0, 0);
            acc2[1][n] = __builtin_amdgcn_mfma_f32_16x16x32_bf16(af2[1], bf2[n], acc2[1][n], 0, 0, 0);
        }
    }

    // ---- +b2, ReLU, dot W3 (VALU), 16-lane reduce, +b3, store ----
    float b2v[4], w3v[4];
#pragma unroll
    for (int n = 0; n < 4; ++n) { b2v[n] = sm.b2s[n * 16 + lo]; w3v[n] = sm.w3s[n * 16 + lo]; }
    float b3s = b3[0];

#pragma unroll
    for (int mt = 0; mt < 2; ++mt)
#pragma unroll
        for (int r = 0; r < 4; ++r) {
            float part = 0.f;
#pragma unroll
            for (int n = 0; n < 4; ++n) {
                float z = fmaxf(acc2[mt][n][r] + b2v[n], 0.f);
                part = fmaf(z, w3v[n], part);
            }
#pragma unroll
            for (int off = 8; off >= 1; off >>= 1) part += __shfl_xor(part, off);
            if (lo == 0) {
                int e = eb + ebl + mt * 16 + hi * 4 + r;
                if (e < E) out[e] = part + b3s;
            }
        }
}

} // namespace

extern "C" void kernel_launch(void* const* d_in, const int* in_sizes, int n_in,
                              void* d_out, int out_size, void* d_ws, size_t ws_size,
                              hipStream_t stream) {
    const float* node_embed = (const float*)d_in[0];
    const int*   eidx       = (const int*)  d_in[1];
    const float* attr       = (const float*)d_in[2];
    const float* W1         = (const float*)d_in[3];
    const float* b1         = (const float*)d_in[4];
    const float* gamma      = (const float*)d_in[5];
    const float* beta       = (const float*)d_in[6];
    const float* W2         = (const float*)d_in[7];
    const float* b2         = (const float*)d_in[8];
    const float* W3         = (const float*)d_in[9];
    const float* b3         = (const float*)d_in[10];
    float* out = (float*)d_out;

    if (ws_size < WS_NEED) return;  // fail loudly via validation rather than corrupt

    char* ws = (char*)d_ws;
    ushort_t* nbf = (ushort_t*)(ws + NB_OFF);
    ushort_t* w1f = (ushort_t*)(ws + W1F_OFF);
    ushort_t* w2f = (ushort_t*)(ws + W2F_OFF);

    cvt_nodes<<<2048, 256, 0, stream>>>(node_embed, nbf, NNODE * H / 4);
    cvt_wfrag<<<80, 64, 0, stream>>>(W1, W2, w1f, w2f);
    edge_mlp_mfma<<<NBLK, 512, 0, stream>>>(nbf, w1f, w2f, eidx, attr, W1, b1,
                                            gamma, beta, b2, W3, b3, out);
}